// Round 14
// baseline (1687.413 us; speedup 1.0000x reference)
//
#include <hip/hip_runtime.h>
#include <hip/hip_bf16.h>
#include <cstdint>
#include <cstddef>

// GRU: T=256, B=128, I=H=1024, 3H=3072. fp32 in/out.
// R14: fragment-native layouts. h is STORED by gate threads directly in MFMA
// A-frag layout; x is pre-transposed into the same layout by the cvt kernel.
// Consumer waves load A-frags with coalesced 16B loads -> hbuf/xbuf LDS
// staging deleted; barriers/step 4 -> 2 (S1, B2). Per-K-quarter counters:
// block arrives on cnt[cg>>3]; wave ks polls cnt[ks] only.
// Frag layout (elem units): [par|t]*131072 + bg*16384 + ks*4096 + kc*512
//   + lane*8 + e, where element = (row=b0+(lane&15), col=ks*256+kc*32+(lane>>4)*8+e).
// Sync rules kept: arrive(no-return L2 atomic) always precedes polls; polls
// are atomic add-0 (never plain sc0 loads — R6 lesson); h data ops sc0 fast /
// sc0sc1 fallback (runtime XCD co-residency check).

typedef __attribute__((ext_vector_type(4))) float f32x4;
typedef __attribute__((ext_vector_type(8))) short s16x8;
typedef __attribute__((ext_vector_type(4))) unsigned short u16x4;

static __device__ __forceinline__ unsigned short f2bf(float f) {
  union { float f; unsigned u; } v; v.f = f;
  unsigned u = v.u;
  u += 0x7FFFu + ((u >> 16) & 1u);   // RNE
  return (unsigned short)(u >> 16);
}
// exp2-native gates
static __device__ __forceinline__ float sigm(float x) {
  float e = __builtin_amdgcn_exp2f(-1.442695041f * x);
  return __builtin_amdgcn_rcpf(1.f + e);
}
static __device__ __forceinline__ float tanh_f(float x) {
  float e = __builtin_amdgcn_exp2f(2.885390082f * x);
  return 1.f - 2.f * __builtin_amdgcn_rcpf(e + 1.f);
}

// L2-scope (XCD-local) data ops
static __device__ __forceinline__ s16x8 ld16_l2(const unsigned short* p) {
  s16x8 r;
  asm volatile("global_load_dwordx4 %0, %1, off sc0" : "=v"(r) : "v"(p) : "memory");
  return r;
}
static __device__ __forceinline__ void st2_l2(unsigned short* p, unsigned short v) {
  unsigned vv = v;
  asm volatile("global_store_short %0, %1, off sc0" :: "v"(p), "v"(vv) : "memory");
}
// device-scope (MALL) data ops
static __device__ __forceinline__ s16x8 ld16_mall(const unsigned short* p) {
  s16x8 r;
  asm volatile("global_load_dwordx4 %0, %1, off sc0 sc1" : "=v"(r) : "v"(p) : "memory");
  return r;
}
static __device__ __forceinline__ void st2_mall(unsigned short* p, unsigned short v) {
  unsigned vv = v;
  asm volatile("global_store_short %0, %1, off sc0 sc1" :: "v"(p), "v"(vv) : "memory");
}
// det flags (once per launch)
static __device__ __forceinline__ void st_flag(unsigned int* p, unsigned v) {
  asm volatile("global_store_dword %0, %1, off sc0 sc1" :: "v"(p), "v"(v) : "memory");
}
static __device__ __forceinline__ unsigned ld_flag(const unsigned int* p) {
  unsigned r;
  asm volatile("global_load_dword %0, %1, off sc0 sc1\n\ts_waitcnt vmcnt(0)"
               : "=v"(r) : "v"(p) : "memory");
  return r;
}
// barrier counter atomics
static __device__ __forceinline__ void add1_l2(unsigned int* p) {
  asm volatile("global_atomic_add %0, %1, off" :: "v"(p), "v"(1u) : "memory");
}
static __device__ __forceinline__ void add1_mall(unsigned int* p) {
  asm volatile("global_atomic_add %0, %1, off sc1" :: "v"(p), "v"(1u) : "memory");
}
static __device__ __forceinline__ unsigned poll_l2(unsigned int* p) {
  unsigned old;
  asm volatile("global_atomic_add %0, %1, %2, off sc0\n\ts_waitcnt vmcnt(0)"
               : "=v"(old) : "v"(p), "v"(0u) : "memory");
  return old;
}
static __device__ __forceinline__ unsigned poll_mall(unsigned int* p) {
  unsigned old;
  asm volatile("global_atomic_add %0, %1, %2, off sc0 sc1\n\ts_waitcnt vmcnt(0)"
               : "=v"(old) : "v"(p), "v"(0u) : "memory");
  return old;
}

// ---------------- Phase 0: f32 -> bf16 + transpose into frag layout ----------------
__global__ __launch_bounds__(256)
void cvt_xfrag(const float* __restrict__ src, unsigned short* __restrict__ dst) {
  const int total = 32768 * 1024 / 8;          // 16B chunks
  int G = blockIdx.x * 256 + threadIdx.x;
  int stride = gridDim.x * 256;
  for (; G < total; G += stride) {
    int t  = G >> 14;
    int r  = G & 16383;
    int bg = r >> 11;
    int q  = r & 2047;
    int ks = q >> 9;
    int w  = q & 511;
    int kc = w >> 6;
    int l  = w & 63;
    int row = bg * 16 + (l & 15);
    int col = ks * 256 + kc * 32 + (l >> 4) * 8;
    const float* s = src + ((size_t)(t * 128 + row)) * 1024 + col;
    f32x4 a = *(const f32x4*)(s);
    f32x4 b = *(const f32x4*)(s + 4);
    s16x8 o;
    o[0] = (short)f2bf(a.x); o[1] = (short)f2bf(a.y);
    o[2] = (short)f2bf(a.z); o[3] = (short)f2bf(a.w);
    o[4] = (short)f2bf(b.x); o[5] = (short)f2bf(b.y);
    o[6] = (short)f2bf(b.z); o[7] = (short)f2bf(b.w);
    *(s16x8*)(dst + (size_t)G * 8) = o;
  }
}

// ---------------- Phase 1: persistent fused GRU scan ----------------
// 256 blocks: bg = id&7 (16 batch rows), cg = id>>3 (32 h-cols).
// 8 waves: ks = wv>>1 (K-quarter), nt = wv&1 (16-col half).
// part slices: 0=r(x+h), 1=z(x+h), 2=n(h only), 3=n(x only).
__global__ __launch_bounds__(512, 1)
void gru_scan(const unsigned short* __restrict__ xfrag, // frag layout, per t
              const float* __restrict__ Whh,            // [3072,1024]
              const float* __restrict__ Wih,            // [3072,1024]
              const float* __restrict__ bhh,            // [3072]
              const float* __restrict__ bih,            // [3072]
              float* __restrict__ out,                  // [256,128,1024]
              unsigned short* __restrict__ hbc,         // 2 parities, frag layout
              unsigned int* __restrict__ bar)           // counters/det
{
  __shared__ float part[8][4][64][4];    // 8 K-slices x 4 part kinds
  __shared__ int fastsh;

  const int tid = threadIdx.x;
  const int lane = tid & 63;
  const int wv = tid >> 6;
  const int id = blockIdx.x;
  const int bg = id & 7;
  const int cg = id >> 3;
  const int c0 = cg * 32;
  const int b0 = bg * 16;
  const int r16 = lane & 15, r4 = lane >> 4;
  const int ks = wv >> 1, nt = wv & 1;

  unsigned int* qcnt  = bar + (size_t)(bg * 4 + ks) * 32;        // wave polls
  unsigned int* mycnt = bar + (size_t)(bg * 4 + (cg >> 3)) * 32; // block arrives
  unsigned int* dflags = bar + 8192 + bg * 32;                   // det flags

  // ---- XCD co-residency detection (HW_REG_XCC_ID) ----
  unsigned myxcc = (__builtin_amdgcn_s_getreg(63508) & 0xFu) | 0x100u;
  if (tid == 0) st_flag(dflags + cg, myxcc);
  if (wv == 0) {
    unsigned v;
    for (;;) {
      v = ld_flag(dflags + (lane & 31));
      if (__ballot(v < 0x100u) == 0) break;
      __builtin_amdgcn_s_sleep(1);
    }
    int bad = (v != myxcc);
    if (tid == 0) fastsh = (__ballot(bad) == 0) ? 1 : 0;
  }
  __syncthreads();
  const bool fast = (fastsh != 0);

  // ---- weight fragments in registers: bwh/bwi[gate][kc] ----
  s16x8 bwh[3][8], bwi[3][8];
  #pragma unroll
  for (int n = 0; n < 3; ++n) {
    const float* hrow = Whh + (size_t)(n * 1024 + c0 + nt * 16 + r16) * 1024;
    const float* irow = Wih + (size_t)(n * 1024 + c0 + nt * 16 + r16) * 1024;
    #pragma unroll
    for (int kc = 0; kc < 8; ++kc) {
      int k = ks * 256 + kc * 32 + r4 * 8;
      f32x4 h0 = *(const f32x4*)(hrow + k);
      f32x4 h1 = *(const f32x4*)(hrow + k + 4);
      f32x4 i0 = *(const f32x4*)(irow + k);
      f32x4 i1 = *(const f32x4*)(irow + k + 4);
      s16x8 fh, fi;
      fh[0] = (short)f2bf(h0.x); fh[1] = (short)f2bf(h0.y);
      fh[2] = (short)f2bf(h0.z); fh[3] = (short)f2bf(h0.w);
      fh[4] = (short)f2bf(h1.x); fh[5] = (short)f2bf(h1.y);
      fh[6] = (short)f2bf(h1.z); fh[7] = (short)f2bf(h1.w);
      fi[0] = (short)f2bf(i0.x); fi[1] = (short)f2bf(i0.y);
      fi[2] = (short)f2bf(i0.z); fi[3] = (short)f2bf(i0.w);
      fi[4] = (short)f2bf(i1.x); fi[5] = (short)f2bf(i1.y);
      fi[6] = (short)f2bf(i1.z); fi[7] = (short)f2bf(i1.w);
      bwh[n][kc] = fh;
      bwi[n][kc] = fi;
    }
  }

  // ---- gate-phase constants: one output (row,col) per thread ----
  const int grow = tid >> 5;          // 0..15
  const int gcolL = tid & 31;         // 0..31
  const int gcol = c0 + gcolL;
  const int g_nt = gcolL >> 4, g_c16 = gcolL & 15;
  const int g_lane = (grow >> 2) * 16 + g_c16;
  const int g_rg = grow & 3;
  const float bR  = bhh[gcol] + bih[gcol];
  const float bZ  = bhh[1024 + gcol] + bih[1024 + gcol];
  const float bNh = bhh[2048 + gcol];
  const float bNx = bih[2048 + gcol];
  float hprev = 0.f;

  // producer h-store index (frag layout)
  const int p_ks = gcol >> 8;
  const int p_kc = (gcol >> 5) & 7;
  const int p_e5 = gcol & 31;
  const int p_l  = ((p_e5 >> 3) << 4) | grow;
  const size_t p_idx = (size_t)bg * 16384 + (size_t)p_ks * 4096 + p_kc * 512
                     + p_l * 8 + (p_e5 & 7);

  // consumer frag bases (coalesced: +lane*8 elems = lane*16B)
  const size_t fbase = (size_t)bg * 16384 + (size_t)ks * 4096 + (size_t)lane * 8;

  for (int t = 0; t < 256; ++t) {
    // ---- x A-frag loads (frag layout, coalesced, cached) — before the poll ----
    const unsigned short* xs = xfrag + (size_t)t * 131072 + fbase;
    s16x8 ax[8];
    #pragma unroll
    for (int kc = 0; kc < 8; ++kc)
      ax[kc] = *(const s16x8*)(xs + kc * 512);

    f32x4 aR = {0.f,0.f,0.f,0.f}, aZ = aR, aNh = aR, aNx = aR;

    if (t > 0) {
      // ---- per-wave poll of own K-quarter counter (arrive preceded this) ----
      unsigned tgt = 8u * (unsigned)t;
      if (fast) {
        for (;;) {
          unsigned v = 0;
          if (lane == 0) v = poll_l2(qcnt);
          v = __shfl(v, 0);
          if (v >= tgt) break;
        }
      } else {
        for (;;) {
          unsigned v = 0;
          if (lane == 0) v = poll_mall(qcnt);
          v = __shfl(v, 0);
          if (v >= tgt) break;
          __builtin_amdgcn_s_sleep(1);
        }
      }

      // ---- h A-frag loads (frag layout, coalesced, sc0) ----
      const unsigned short* hs = hbc + (size_t)(t & 1) * 131072 + fbase;
      s16x8 ah[8];
      if (fast) {
        #pragma unroll
        for (int kc = 0; kc < 8; ++kc)
          ah[kc] = ld16_l2(hs + kc * 512);
      } else {
        #pragma unroll
        for (int kc = 0; kc < 8; ++kc)
          ah[kc] = ld16_mall(hs + kc * 512);
      }
      asm volatile("s_waitcnt vmcnt(0)" ::: "memory");
      __builtin_amdgcn_sched_barrier(0);

      #pragma unroll
      for (int kc = 0; kc < 8; ++kc) {
        aR  = __builtin_amdgcn_mfma_f32_16x16x32_bf16(ah[kc], bwh[0][kc], aR, 0, 0, 0);
        aR  = __builtin_amdgcn_mfma_f32_16x16x32_bf16(ax[kc], bwi[0][kc], aR, 0, 0, 0);
        aZ  = __builtin_amdgcn_mfma_f32_16x16x32_bf16(ah[kc], bwh[1][kc], aZ, 0, 0, 0);
        aZ  = __builtin_amdgcn_mfma_f32_16x16x32_bf16(ax[kc], bwi[1][kc], aZ, 0, 0, 0);
        aNh = __builtin_amdgcn_mfma_f32_16x16x32_bf16(ah[kc], bwh[2][kc], aNh, 0, 0, 0);
        aNx = __builtin_amdgcn_mfma_f32_16x16x32_bf16(ax[kc], bwi[2][kc], aNx, 0, 0, 0);
      }
    } else {
      // t == 0: h = 0 exactly -> x-MFMAs only (no hbc read, no memset needed)
      #pragma unroll
      for (int kc = 0; kc < 8; ++kc) {
        aR  = __builtin_amdgcn_mfma_f32_16x16x32_bf16(ax[kc], bwi[0][kc], aR, 0, 0, 0);
        aZ  = __builtin_amdgcn_mfma_f32_16x16x32_bf16(ax[kc], bwi[1][kc], aZ, 0, 0, 0);
        aNx = __builtin_amdgcn_mfma_f32_16x16x32_bf16(ax[kc], bwi[2][kc], aNx, 0, 0, 0);
      }
    }

    *(f32x4*)&part[wv][0][lane][0] = aR;
    *(f32x4*)&part[wv][1][lane][0] = aZ;
    *(f32x4*)&part[wv][2][lane][0] = aNh;
    *(f32x4*)&part[wv][3][lane][0] = aNx;
    __syncthreads();                                   // S1

    // ---- gates: every thread owns (grow, gcolL) ----
    {
      float sr = bR, sz = bZ, snh = bNh, snx = bNx;
      #pragma unroll
      for (int kx = 0; kx < 4; ++kx) {
        sr  += part[kx * 2 + g_nt][0][g_lane][g_rg];
        sz  += part[kx * 2 + g_nt][1][g_lane][g_rg];
        snh += part[kx * 2 + g_nt][2][g_lane][g_rg];
        snx += part[kx * 2 + g_nt][3][g_lane][g_rg];
      }
      float rg = sigm(sr);
      float zg = sigm(sz);
      float ng = tanh_f(snx + rg * snh);
      float h = (1.f - zg) * ng + zg * hprev;
      hprev = h;
      unsigned short hv = f2bf(h);
      unsigned short* wH = hbc + (size_t)((t + 1) & 1) * 131072;
      if (fast) st2_l2(wH + p_idx, hv);
      else      st2_mall(wH + p_idx, hv);
      out[(size_t)t * 131072 + (size_t)(b0 + grow) * 1024 + gcol] = h;
      asm volatile("s_waitcnt vmcnt(1)" ::: "memory"); // h acked; out in flight
    }
    __syncthreads();                                   // B2

    // arrive on own quarter (always precedes next iteration's polls)
    if (tid == 0) {
      if (fast) add1_l2(mycnt);
      else      add1_mall(mycnt);
    }
  }
}

extern "C" void kernel_launch(void* const* d_in, const int* in_sizes, int n_in,
                              void* d_out, int out_size, void* d_ws, size_t ws_size,
                              hipStream_t stream) {
  const float* x   = (const float*)d_in[0];
  const float* wih = (const float*)d_in[1];
  const float* whh = (const float*)d_in[2];
  const float* bih = (const float*)d_in[3];
  const float* bhh = (const float*)d_in[4];
  float* out = (float*)d_out;

  char* ws = (char*)d_ws;
  unsigned short* xfrag = (unsigned short*)ws;                    // 64 MiB
  unsigned short* hbc   = (unsigned short*)(ws + 67108864);       // 512 KiB
  unsigned int*   bar   = (unsigned int*)(ws + 67633152);         // 40 KiB

  hipMemsetAsync(bar, 0, 40960, stream);    // counters + det flags
  cvt_xfrag<<<2048, 256, 0, stream>>>(x, xfrag);
  gru_scan<<<256, 512, 0, stream>>>(xfrag, whh, wih, bhh, bih, out, hbc, bar);
}

// Round 15
// 1577.039 us; speedup vs baseline: 1.0700x; 1.0700x over previous
//
#include <hip/hip_runtime.h>
#include <hip/hip_bf16.h>
#include <cstdint>
#include <cstddef>

// GRU: T=256, B=128, I=H=1024, 3H=3072. fp32 in/out.
// R15 = R13 + (a) conflict-free part[] layout [8][4][4][64] (b32 lane-stride-4
// writes; was b128 lane-stride-16 = 8-way bank alias, 8.4e7 conflict cycles),
// (b) B2 deleted: wave-granular arrive after the wave-scoped vmcnt(1) drain
// (s_waitcnt is per-wave, so each wave's h-stores are acked when its lane0
// arrives). ONE poller per block (R14 lesson: poller storms saturate L2
// atomics). Sync rules: arrive always precedes poll (in-wave for wv7);
// polls are atomic add-0, never plain sc0 loads (R6); staging via coalesced
// LDS (R10/R12); counters memset per launch.

typedef __attribute__((ext_vector_type(4))) float f32x4;
typedef __attribute__((ext_vector_type(8))) short s16x8;
typedef __attribute__((ext_vector_type(4))) unsigned short u16x4;

static __device__ __forceinline__ unsigned short f2bf(float f) {
  union { float f; unsigned u; } v; v.f = f;
  unsigned u = v.u;
  u += 0x7FFFu + ((u >> 16) & 1u);   // RNE
  return (unsigned short)(u >> 16);
}
static __device__ __forceinline__ float bf2f(unsigned short h) {
  union { unsigned u; float f; } v; v.u = ((unsigned)h) << 16;
  return v.f;
}
// exp2-native gates (pure arithmetic)
static __device__ __forceinline__ float sigm(float x) {
  float e = __builtin_amdgcn_exp2f(-1.442695041f * x);
  return __builtin_amdgcn_rcpf(1.f + e);
}
static __device__ __forceinline__ float tanh_f(float x) {
  float e = __builtin_amdgcn_exp2f(2.885390082f * x);
  return 1.f - 2.f * __builtin_amdgcn_rcpf(e + 1.f);
}

// L2-scope (XCD-local) data ops
static __device__ __forceinline__ s16x8 ld16_l2(const unsigned short* p) {
  s16x8 r;
  asm volatile("global_load_dwordx4 %0, %1, off sc0" : "=v"(r) : "v"(p) : "memory");
  return r;
}
static __device__ __forceinline__ void st2_l2(unsigned short* p, unsigned short v) {
  unsigned vv = v;
  asm volatile("global_store_short %0, %1, off sc0" :: "v"(p), "v"(vv) : "memory");
}
// device-scope (MALL) data ops
static __device__ __forceinline__ s16x8 ld16_mall(const unsigned short* p) {
  s16x8 r;
  asm volatile("global_load_dwordx4 %0, %1, off sc0 sc1" : "=v"(r) : "v"(p) : "memory");
  return r;
}
static __device__ __forceinline__ void st2_mall(unsigned short* p, unsigned short v) {
  unsigned vv = v;
  asm volatile("global_store_short %0, %1, off sc0 sc1" :: "v"(p), "v"(vv) : "memory");
}
// det flags (once per launch): MALL loads/stores
static __device__ __forceinline__ void st_flag(unsigned int* p, unsigned v) {
  asm volatile("global_store_dword %0, %1, off sc0 sc1" :: "v"(p), "v"(v) : "memory");
}
static __device__ __forceinline__ unsigned ld_flag(const unsigned int* p) {
  unsigned r;
  asm volatile("global_load_dword %0, %1, off sc0 sc1\n\ts_waitcnt vmcnt(0)"
               : "=v"(r) : "v"(p) : "memory");
  return r;
}
// barrier counter atomics
static __device__ __forceinline__ void add1_l2(unsigned int* p) {
  asm volatile("global_atomic_add %0, %1, off" :: "v"(p), "v"(1u) : "memory");
}
static __device__ __forceinline__ void add1_mall(unsigned int* p) {
  asm volatile("global_atomic_add %0, %1, off sc1" :: "v"(p), "v"(1u) : "memory");
}
static __device__ __forceinline__ unsigned poll_l2(unsigned int* p) {
  unsigned old;
  asm volatile("global_atomic_add %0, %1, %2, off sc0\n\ts_waitcnt vmcnt(0)"
               : "=v"(old) : "v"(p), "v"(0u) : "memory");
  return old;
}
static __device__ __forceinline__ unsigned poll_mall(unsigned int* p) {
  unsigned old;
  asm volatile("global_atomic_add %0, %1, %2, off sc0 sc1\n\ts_waitcnt vmcnt(0)"
               : "=v"(old) : "v"(p), "v"(0u) : "memory");
  return old;
}

// ---------------- Phase 0: f32 -> bf16 convert (x only) ----------------
__global__ __launch_bounds__(256)
void cvt_bf16(const float* __restrict__ src, unsigned short* __restrict__ dst, int n4) {
  int i = blockIdx.x * 256 + threadIdx.x;
  int stride = gridDim.x * 256;
  for (; i < n4; i += stride) {
    f32x4 v = ((const f32x4*)src)[i];
    u16x4 o = { f2bf(v.x), f2bf(v.y), f2bf(v.z), f2bf(v.w) };
    ((u16x4*)dst)[i] = o;
  }
}

// ---------------- Phase 1: persistent fused GRU scan ----------------
// 256 blocks: bg = id&7 (16 batch rows), cg = id>>3 (32 h-cols).
// 8 waves: ks = wv>>1 (K-quarter), nt = wv&1 (16-col half).
// part slices: 0=r(x+h), 1=z(x+h), 2=n(h only), 3=n(x only).
__global__ __launch_bounds__(512, 1)
void gru_scan(const unsigned short* __restrict__ xbf,  // [32768,1024] bf16
              const float* __restrict__ Whh,           // [3072,1024]
              const float* __restrict__ Wih,           // [3072,1024]
              const float* __restrict__ bhh,           // [3072]
              const float* __restrict__ bih,           // [3072]
              float* __restrict__ out,                 // [256,128,1024]
              unsigned short* __restrict__ hbc,        // 2 x [128][1024] bf16
              unsigned int* __restrict__ bar)          // counter/det regions
{
  __shared__ char hbuf[32768];           // swizzled [16][1024] bf16 h tile
  __shared__ char xbuf[32768];           // swizzled [16][1024] bf16 x tile
  __shared__ float part[8][4][4][64];    // [kslice][kind][reg][lane] — b32, conflict-free
  __shared__ int fastsh;

  const int tid = threadIdx.x;
  const int lane = tid & 63;
  const int wv = tid >> 6;
  const int id = blockIdx.x;
  const int bg = id & 7;
  const int cg = id >> 3;
  const int c0 = cg * 32;
  const int b0 = bg * 16;
  const int r16 = lane & 15, r4 = lane >> 4;
  const int ks = wv >> 1, nt = wv & 1;

  unsigned int* cnt = bar + bg * 32;              // one 128B line per bg
  unsigned int* dflags = bar + 8192 + bg * 32;    // dense det flags

  // ---- XCD co-residency detection (HW_REG_XCC_ID) ----
  unsigned myxcc = (__builtin_amdgcn_s_getreg(63508) & 0xFu) | 0x100u;
  if (tid == 0) st_flag(dflags + cg, myxcc);
  if (wv == 0) {
    unsigned v;
    for (;;) {
      v = ld_flag(dflags + (lane & 31));
      if (__ballot(v < 0x100u) == 0) break;
      __builtin_amdgcn_s_sleep(1);
    }
    int bad = (v != myxcc);
    if (tid == 0) fastsh = (__ballot(bad) == 0) ? 1 : 0;
  }
  __syncthreads();
  const bool fast = (fastsh != 0);

  // ---- weight fragments in registers: bwh/bwi[gate][kc] ----
  s16x8 bwh[3][8], bwi[3][8];
  #pragma unroll
  for (int n = 0; n < 3; ++n) {
    const float* hrow = Whh + (size_t)(n * 1024 + c0 + nt * 16 + r16) * 1024;
    const float* irow = Wih + (size_t)(n * 1024 + c0 + nt * 16 + r16) * 1024;
    #pragma unroll
    for (int kc = 0; kc < 8; ++kc) {
      int k = ks * 256 + kc * 32 + r4 * 8;
      f32x4 h0 = *(const f32x4*)(hrow + k);
      f32x4 h1 = *(const f32x4*)(hrow + k + 4);
      f32x4 i0 = *(const f32x4*)(irow + k);
      f32x4 i1 = *(const f32x4*)(irow + k + 4);
      s16x8 fh, fi;
      fh[0] = (short)f2bf(h0.x); fh[1] = (short)f2bf(h0.y);
      fh[2] = (short)f2bf(h0.z); fh[3] = (short)f2bf(h0.w);
      fh[4] = (short)f2bf(h1.x); fh[5] = (short)f2bf(h1.y);
      fh[6] = (short)f2bf(h1.z); fh[7] = (short)f2bf(h1.w);
      fi[0] = (short)f2bf(i0.x); fi[1] = (short)f2bf(i0.y);
      fi[2] = (short)f2bf(i0.z); fi[3] = (short)f2bf(i0.w);
      fi[4] = (short)f2bf(i1.x); fi[5] = (short)f2bf(i1.y);
      fi[6] = (short)f2bf(i1.z); fi[7] = (short)f2bf(i1.w);
      bwh[n][kc] = fh;
      bwi[n][kc] = fi;
    }
  }

  // ---- gate-phase constants: one output (row,col) per thread ----
  const int grow = tid >> 5;          // 0..15
  const int gcolL = tid & 31;         // 0..31
  const int gcol = c0 + gcolL;
  const int g_nt = gcolL >> 4, g_c16 = gcolL & 15;
  const int g_lane = (grow >> 2) * 16 + g_c16;
  const int g_rg = grow & 3;
  const float bR  = bhh[gcol] + bih[gcol];
  const float bZ  = bhh[1024 + gcol] + bih[1024 + gcol];
  const float bNh = bhh[2048 + gcol];
  const float bNx = bih[2048 + gcol];
  float hprev = 0.f;

  // A-frag read addressing (swizzled) — shared by hbuf and xbuf
  const int arow = lane & 15;
  const int aswz = (arow & 7) << 4;
  const int abase = arow * 2048;
  const int g16 = (lane >> 4) * 16;

  // staging addressing: rows {i*4+ks}, colbyte = nt*1024 + lane*16
  const int scb = nt * 1024 + lane * 16;
  int s_goff[4], s_loff[4];
  #pragma unroll
  for (int i = 0; i < 4; ++i) {
    int row = i * 4 + ks;
    s_goff[i] = (b0 + row) * 1024 + (scb >> 1);          // elem off
    s_loff[i] = row * 2048 + (scb ^ ((row & 7) << 4));   // lds byte off
  }

  // ---- prologue: h[0]=0 in hbuf; stage x[0] into xbuf ----
  #pragma unroll
  for (int i = 0; i < 4; ++i)
    *(f32x4*)(hbuf + tid * 64 + i * 16) = (f32x4){0.f, 0.f, 0.f, 0.f};
  {
    s16x8 v0 = *(const s16x8*)(xbf + s_goff[0]);
    s16x8 v1 = *(const s16x8*)(xbf + s_goff[1]);
    s16x8 v2 = *(const s16x8*)(xbf + s_goff[2]);
    s16x8 v3 = *(const s16x8*)(xbf + s_goff[3]);
    *(s16x8*)(xbuf + s_loff[0]) = v0;
    *(s16x8*)(xbuf + s_loff[1]) = v1;
    *(s16x8*)(xbuf + s_loff[2]) = v2;
    *(s16x8*)(xbuf + s_loff[3]) = v3;
  }
  __syncthreads();

  for (int t = 0; t < 256; ++t) {
    // ---- MFMA: x- and h-projections, fp32 accum ----
    f32x4 aR = {0.f,0.f,0.f,0.f}, aZ = aR, aNh = aR, aNx = aR;
    #pragma unroll
    for (int kc = 0; kc < 8; ++kc) {
      int off = (ks * 512 + kc * 64 + g16) ^ aswz;
      s16x8 ah = *(const s16x8*)(hbuf + abase + off);
      s16x8 ax = *(const s16x8*)(xbuf + abase + off);
      aR  = __builtin_amdgcn_mfma_f32_16x16x32_bf16(ah, bwh[0][kc], aR, 0, 0, 0);
      aR  = __builtin_amdgcn_mfma_f32_16x16x32_bf16(ax, bwi[0][kc], aR, 0, 0, 0);
      aZ  = __builtin_amdgcn_mfma_f32_16x16x32_bf16(ah, bwh[1][kc], aZ, 0, 0, 0);
      aZ  = __builtin_amdgcn_mfma_f32_16x16x32_bf16(ax, bwi[1][kc], aZ, 0, 0, 0);
      aNh = __builtin_amdgcn_mfma_f32_16x16x32_bf16(ah, bwh[2][kc], aNh, 0, 0, 0);
      aNx = __builtin_amdgcn_mfma_f32_16x16x32_bf16(ax, bwi[2][kc], aNx, 0, 0, 0);
    }
    // conflict-free b32 partial writes (lane-stride 4B)
    #pragma unroll
    for (int r = 0; r < 4; ++r) {
      part[wv][0][r][lane] = aR[r];
      part[wv][1][r][lane] = aZ[r];
      part[wv][2][r][lane] = aNh[r];
      part[wv][3][r][lane] = aNx[r];
    }
    __syncthreads();                                   // S1

    // ---- gates: every thread owns (grow, gcolL) ----
    {
      float sr = bR, sz = bZ, snh = bNh, snx = bNx;
      #pragma unroll
      for (int kx = 0; kx < 4; ++kx) {
        sr  += part[kx * 2 + g_nt][0][g_rg][g_lane];
        sz  += part[kx * 2 + g_nt][1][g_rg][g_lane];
        snh += part[kx * 2 + g_nt][2][g_rg][g_lane];
        snx += part[kx * 2 + g_nt][3][g_rg][g_lane];
      }
      float rg = sigm(sr);
      float zg = sigm(sz);
      float ng = tanh_f(snx + rg * snh);
      float h = (1.f - zg) * ng + zg * hprev;
      hprev = h;
      unsigned short* wH = hbc + (size_t)((t + 1) & 1) * 131072;
      size_t widx = (size_t)(b0 + grow) * 1024 + gcol;
      if (fast) st2_l2(wH + widx, f2bf(h));
      else      st2_mall(wH + widx, f2bf(h));
      out[(size_t)t * 131072 + widx] = h;              // after h store (program order)
      asm volatile("s_waitcnt vmcnt(1)" ::: "memory"); // wave's h stores acked
    }

    // wave-granular arrival: this wave's h is drained (vmcnt is wave-scoped)
    if (lane == 0) {
      if (fast) add1_l2(cnt);
      else      add1_mall(cnt);
    }

    if (t < 255) {
      // ---- x[t+1] staging issue (plain cached loads); overlaps the poll ----
      size_t xb = (size_t)(t + 1) * 131072;
      s16x8 x0 = *(const s16x8*)(xbf + xb + s_goff[0]);
      s16x8 x1 = *(const s16x8*)(xbf + xb + s_goff[1]);
      s16x8 x2 = *(const s16x8*)(xbf + xb + s_goff[2]);
      s16x8 x3 = *(const s16x8*)(xbf + xb + s_goff[3]);

      // single poller: wv7/lane0 polls the bg counter (its wave arrived above)
      if (wv == 7 && lane == 0) {
        unsigned tgt = 256u * (unsigned)(t + 1);       // 8 waves x 32 blocks
        if (fast) {
          while (poll_l2(cnt) < tgt) {}
        } else {
          while (poll_mall(cnt) < tgt) __builtin_amdgcn_s_sleep(1);
        }
      }
      *(s16x8*)(xbuf + s_loff[0]) = x0;
      *(s16x8*)(xbuf + s_loff[1]) = x1;
      *(s16x8*)(xbuf + s_loff[2]) = x2;
      *(s16x8*)(xbuf + s_loff[3]) = x3;
      __syncthreads();                                 // S2

      // ---- stage h[t+1] into hbuf (coalesced L2 loads, swizzled LDS) ----
      const unsigned short* hs = hbc + (size_t)((t + 1) & 1) * 131072;
      s16x8 v0, v1, v2, v3;
      if (fast) {
        v0 = ld16_l2(hs + s_goff[0]); v1 = ld16_l2(hs + s_goff[1]);
        v2 = ld16_l2(hs + s_goff[2]); v3 = ld16_l2(hs + s_goff[3]);
      } else {
        v0 = ld16_mall(hs + s_goff[0]); v1 = ld16_mall(hs + s_goff[1]);
        v2 = ld16_mall(hs + s_goff[2]); v3 = ld16_mall(hs + s_goff[3]);
      }
      asm volatile("s_waitcnt vmcnt(0)" ::: "memory");
      *(s16x8*)(hbuf + s_loff[0]) = v0;
      *(s16x8*)(hbuf + s_loff[1]) = v1;
      *(s16x8*)(hbuf + s_loff[2]) = v2;
      *(s16x8*)(hbuf + s_loff[3]) = v3;
      __syncthreads();                                 // S3
    }
  }
}

extern "C" void kernel_launch(void* const* d_in, const int* in_sizes, int n_in,
                              void* d_out, int out_size, void* d_ws, size_t ws_size,
                              hipStream_t stream) {
  const float* x   = (const float*)d_in[0];
  const float* wih = (const float*)d_in[1];
  const float* whh = (const float*)d_in[2];
  const float* bih = (const float*)d_in[3];
  const float* bhh = (const float*)d_in[4];
  float* out = (float*)d_out;

  char* ws = (char*)d_ws;
  unsigned short* xbf = (unsigned short*)ws;                      // 64 MiB
  unsigned short* hbc = (unsigned short*)(ws + 67108864);         // 512 KiB
  unsigned int*   bar = (unsigned int*)(ws + 67633152);           // 40 KiB

  hipMemsetAsync(bar, 0, 40960, stream);    // counters + det flags
  cvt_bf16<<<2048, 256, 0, stream>>>(x, xbf, 32768 * 1024 / 4);
  gru_scan<<<256, 512, 0, stream>>>(xbf, whh, wih, bhh, bih, out, hbc, bar);
}

// Round 16
// 803.911 us; speedup vs baseline: 2.0990x; 1.9617x over previous
//
#include <hip/hip_runtime.h>
#include <hip/hip_bf16.h>
#include <cstdint>
#include <cstddef>

// GRU: T=256, B=128, I=H=1024, 3H=3072. fp32 in/out.
// R16 = R13 + ONE change: part[] relayout to [kslice][kind][reg][lane]
// (b32 lane-stride-4 writes/reads, conflict-free) — everything else,
// especially the sync protocol, is R13 byte-for-byte.
// PROVEN sync protocol: S1 / gates+h-store+vmcnt(1) / B2 / tid0 add1(L2) /
// x-stage issue / wv7-lane0 poll (atomic add-0) / S2 / h-stage / S3.
// Rules learned: one arrival + one poller per block (R14/R15); polls are
// atomics never sc0 loads (R6); staging coalesced via LDS (R10/R12).

typedef __attribute__((ext_vector_type(4))) float f32x4;
typedef __attribute__((ext_vector_type(8))) short s16x8;
typedef __attribute__((ext_vector_type(4))) unsigned short u16x4;

static __device__ __forceinline__ unsigned short f2bf(float f) {
  union { float f; unsigned u; } v; v.f = f;
  unsigned u = v.u;
  u += 0x7FFFu + ((u >> 16) & 1u);   // RNE
  return (unsigned short)(u >> 16);
}
static __device__ __forceinline__ float bf2f(unsigned short h) {
  union { unsigned u; float f; } v; v.u = ((unsigned)h) << 16;
  return v.f;
}
// exp2-native gates (pure arithmetic)
static __device__ __forceinline__ float sigm(float x) {
  float e = __builtin_amdgcn_exp2f(-1.442695041f * x);
  return __builtin_amdgcn_rcpf(1.f + e);
}
static __device__ __forceinline__ float tanh_f(float x) {
  float e = __builtin_amdgcn_exp2f(2.885390082f * x);
  return 1.f - 2.f * __builtin_amdgcn_rcpf(e + 1.f);
}

// L2-scope (XCD-local) data ops
static __device__ __forceinline__ s16x8 ld16_l2(const unsigned short* p) {
  s16x8 r;
  asm volatile("global_load_dwordx4 %0, %1, off sc0" : "=v"(r) : "v"(p) : "memory");
  return r;
}
static __device__ __forceinline__ void st2_l2(unsigned short* p, unsigned short v) {
  unsigned vv = v;
  asm volatile("global_store_short %0, %1, off sc0" :: "v"(p), "v"(vv) : "memory");
}
// device-scope (MALL) data ops
static __device__ __forceinline__ s16x8 ld16_mall(const unsigned short* p) {
  s16x8 r;
  asm volatile("global_load_dwordx4 %0, %1, off sc0 sc1" : "=v"(r) : "v"(p) : "memory");
  return r;
}
static __device__ __forceinline__ void st2_mall(unsigned short* p, unsigned short v) {
  unsigned vv = v;
  asm volatile("global_store_short %0, %1, off sc0 sc1" :: "v"(p), "v"(vv) : "memory");
}
// det flags (once per launch): MALL loads/stores
static __device__ __forceinline__ void st_flag(unsigned int* p, unsigned v) {
  asm volatile("global_store_dword %0, %1, off sc0 sc1" :: "v"(p), "v"(v) : "memory");
}
static __device__ __forceinline__ unsigned ld_flag(const unsigned int* p) {
  unsigned r;
  asm volatile("global_load_dword %0, %1, off sc0 sc1\n\ts_waitcnt vmcnt(0)"
               : "=v"(r) : "v"(p) : "memory");
  return r;
}
// barrier counter atomics
static __device__ __forceinline__ void add1_l2(unsigned int* p) {
  asm volatile("global_atomic_add %0, %1, off" :: "v"(p), "v"(1u) : "memory");
}
static __device__ __forceinline__ void add1_mall(unsigned int* p) {
  asm volatile("global_atomic_add %0, %1, off sc1" :: "v"(p), "v"(1u) : "memory");
}
static __device__ __forceinline__ unsigned poll_l2(unsigned int* p) {
  unsigned old;
  asm volatile("global_atomic_add %0, %1, %2, off sc0\n\ts_waitcnt vmcnt(0)"
               : "=v"(old) : "v"(p), "v"(0u) : "memory");
  return old;
}
static __device__ __forceinline__ unsigned poll_mall(unsigned int* p) {
  unsigned old;
  asm volatile("global_atomic_add %0, %1, %2, off sc0 sc1\n\ts_waitcnt vmcnt(0)"
               : "=v"(old) : "v"(p), "v"(0u) : "memory");
  return old;
}

// ---------------- Phase 0: f32 -> bf16 convert (x only) ----------------
__global__ __launch_bounds__(256)
void cvt_bf16(const float* __restrict__ src, unsigned short* __restrict__ dst, int n4) {
  int i = blockIdx.x * 256 + threadIdx.x;
  int stride = gridDim.x * 256;
  for (; i < n4; i += stride) {
    f32x4 v = ((const f32x4*)src)[i];
    u16x4 o = { f2bf(v.x), f2bf(v.y), f2bf(v.z), f2bf(v.w) };
    ((u16x4*)dst)[i] = o;
  }
}

// ---------------- Phase 1: persistent fused GRU scan ----------------
// 256 blocks: bg = id&7 (16 batch rows), cg = id>>3 (32 h-cols).
// 8 waves: ks = wv>>1 (K-quarter), nt = wv&1 (16-col half).
// part slices: 0=r(x+h), 1=z(x+h), 2=n(h only), 3=n(x only).
__global__ __launch_bounds__(512, 1)
void gru_scan(const unsigned short* __restrict__ xbf,  // [32768,1024] bf16
              const float* __restrict__ Whh,           // [3072,1024]
              const float* __restrict__ Wih,           // [3072,1024]
              const float* __restrict__ bhh,           // [3072]
              const float* __restrict__ bih,           // [3072]
              float* __restrict__ out,                 // [256,128,1024]
              unsigned short* __restrict__ hbc,        // 2 x [128][1024] bf16
              unsigned int* __restrict__ bar)          // counter/det regions
{
  __shared__ char hbuf[32768];           // swizzled [16][1024] bf16 h tile
  __shared__ char xbuf[32768];           // swizzled [16][1024] bf16 x tile
  __shared__ float part[8][4][4][64];    // [kslice][kind][reg][lane] b32 conflict-free
  __shared__ int fastsh;

  const int tid = threadIdx.x;
  const int lane = tid & 63;
  const int wv = tid >> 6;
  const int id = blockIdx.x;
  const int bg = id & 7;
  const int cg = id >> 3;
  const int c0 = cg * 32;
  const int b0 = bg * 16;
  const int r16 = lane & 15, r4 = lane >> 4;
  const int ks = wv >> 1, nt = wv & 1;

  unsigned int* cnt = bar + bg * 32;              // one 128B line per bg
  unsigned int* dflags = bar + 8192 + bg * 32;    // dense det flags

  // ---- XCD co-residency detection (HW_REG_XCC_ID) ----
  unsigned myxcc = (__builtin_amdgcn_s_getreg(63508) & 0xFu) | 0x100u;
  if (tid == 0) st_flag(dflags + cg, myxcc);
  if (wv == 0) {
    unsigned v;
    for (;;) {
      v = ld_flag(dflags + (lane & 31));
      if (__ballot(v < 0x100u) == 0) break;
      __builtin_amdgcn_s_sleep(1);
    }
    int bad = (v != myxcc);
    if (tid == 0) fastsh = (__ballot(bad) == 0) ? 1 : 0;
  }
  __syncthreads();
  const bool fast = (fastsh != 0);

  // ---- weight fragments in registers: bwh/bwi[gate][kc] ----
  s16x8 bwh[3][8], bwi[3][8];
  #pragma unroll
  for (int n = 0; n < 3; ++n) {
    const float* hrow = Whh + (size_t)(n * 1024 + c0 + nt * 16 + r16) * 1024;
    const float* irow = Wih + (size_t)(n * 1024 + c0 + nt * 16 + r16) * 1024;
    #pragma unroll
    for (int kc = 0; kc < 8; ++kc) {
      int k = ks * 256 + kc * 32 + r4 * 8;
      f32x4 h0 = *(const f32x4*)(hrow + k);
      f32x4 h1 = *(const f32x4*)(hrow + k + 4);
      f32x4 i0 = *(const f32x4*)(irow + k);
      f32x4 i1 = *(const f32x4*)(irow + k + 4);
      s16x8 fh, fi;
      fh[0] = (short)f2bf(h0.x); fh[1] = (short)f2bf(h0.y);
      fh[2] = (short)f2bf(h0.z); fh[3] = (short)f2bf(h0.w);
      fh[4] = (short)f2bf(h1.x); fh[5] = (short)f2bf(h1.y);
      fh[6] = (short)f2bf(h1.z); fh[7] = (short)f2bf(h1.w);
      fi[0] = (short)f2bf(i0.x); fi[1] = (short)f2bf(i0.y);
      fi[2] = (short)f2bf(i0.z); fi[3] = (short)f2bf(i0.w);
      fi[4] = (short)f2bf(i1.x); fi[5] = (short)f2bf(i1.y);
      fi[6] = (short)f2bf(i1.z); fi[7] = (short)f2bf(i1.w);
      bwh[n][kc] = fh;
      bwi[n][kc] = fi;
    }
  }

  // ---- gate-phase constants: one output (row,col) per thread ----
  const int grow = tid >> 5;          // 0..15
  const int gcolL = tid & 31;         // 0..31
  const int gcol = c0 + gcolL;
  const int g_nt = gcolL >> 4, g_c16 = gcolL & 15;
  const int g_lane = (grow >> 2) * 16 + g_c16;
  const int g_rg = grow & 3;
  const float bR  = bhh[gcol] + bih[gcol];
  const float bZ  = bhh[1024 + gcol] + bih[1024 + gcol];
  const float bNh = bhh[2048 + gcol];
  const float bNx = bih[2048 + gcol];
  float hprev = 0.f;

  // A-frag read addressing (swizzled) — shared by hbuf and xbuf
  const int arow = lane & 15;
  const int aswz = (arow & 7) << 4;
  const int abase = arow * 2048;
  const int g16 = (lane >> 4) * 16;

  // staging addressing: rows {i*4+ks}, colbyte = nt*1024 + lane*16
  const int scb = nt * 1024 + lane * 16;
  int s_goff[4], s_loff[4];
  #pragma unroll
  for (int i = 0; i < 4; ++i) {
    int row = i * 4 + ks;
    s_goff[i] = (b0 + row) * 1024 + (scb >> 1);          // elem off
    s_loff[i] = row * 2048 + (scb ^ ((row & 7) << 4));   // lds byte off
  }

  // ---- prologue: h[0]=0 in hbuf; stage x[0] into xbuf ----
  #pragma unroll
  for (int i = 0; i < 4; ++i)
    *(f32x4*)(hbuf + tid * 64 + i * 16) = (f32x4){0.f, 0.f, 0.f, 0.f};
  {
    s16x8 v0 = *(const s16x8*)(xbf + s_goff[0]);
    s16x8 v1 = *(const s16x8*)(xbf + s_goff[1]);
    s16x8 v2 = *(const s16x8*)(xbf + s_goff[2]);
    s16x8 v3 = *(const s16x8*)(xbf + s_goff[3]);
    *(s16x8*)(xbuf + s_loff[0]) = v0;
    *(s16x8*)(xbuf + s_loff[1]) = v1;
    *(s16x8*)(xbuf + s_loff[2]) = v2;
    *(s16x8*)(xbuf + s_loff[3]) = v3;
  }
  __syncthreads();

  for (int t = 0; t < 256; ++t) {
    // ---- MFMA: x- and h-projections, fp32 accum ----
    f32x4 aR = {0.f,0.f,0.f,0.f}, aZ = aR, aNh = aR, aNx = aR;
    #pragma unroll
    for (int kc = 0; kc < 8; ++kc) {
      int off = (ks * 512 + kc * 64 + g16) ^ aswz;
      s16x8 ah = *(const s16x8*)(hbuf + abase + off);
      s16x8 ax = *(const s16x8*)(xbuf + abase + off);
      aR  = __builtin_amdgcn_mfma_f32_16x16x32_bf16(ah, bwh[0][kc], aR, 0, 0, 0);
      aR  = __builtin_amdgcn_mfma_f32_16x16x32_bf16(ax, bwi[0][kc], aR, 0, 0, 0);
      aZ  = __builtin_amdgcn_mfma_f32_16x16x32_bf16(ah, bwh[1][kc], aZ, 0, 0, 0);
      aZ  = __builtin_amdgcn_mfma_f32_16x16x32_bf16(ax, bwi[1][kc], aZ, 0, 0, 0);
      aNh = __builtin_amdgcn_mfma_f32_16x16x32_bf16(ah, bwh[2][kc], aNh, 0, 0, 0);
      aNx = __builtin_amdgcn_mfma_f32_16x16x32_bf16(ax, bwi[2][kc], aNx, 0, 0, 0);
    }
    // conflict-free b32 partial writes (lane-stride 4B)
    #pragma unroll
    for (int r = 0; r < 4; ++r) {
      part[wv][0][r][lane] = aR[r];
      part[wv][1][r][lane] = aZ[r];
      part[wv][2][r][lane] = aNh[r];
      part[wv][3][r][lane] = aNx[r];
    }
    __syncthreads();                                   // S1

    // ---- gates: every thread owns (grow, gcolL) ----
    {
      float sr = bR, sz = bZ, snh = bNh, snx = bNx;
      #pragma unroll
      for (int kx = 0; kx < 4; ++kx) {
        sr  += part[kx * 2 + g_nt][0][g_rg][g_lane];
        sz  += part[kx * 2 + g_nt][1][g_rg][g_lane];
        snh += part[kx * 2 + g_nt][2][g_rg][g_lane];
        snx += part[kx * 2 + g_nt][3][g_rg][g_lane];
      }
      float rg = sigm(sr);
      float zg = sigm(sz);
      float ng = tanh_f(snx + rg * snh);
      float h = (1.f - zg) * ng + zg * hprev;
      hprev = h;
      unsigned short* wH = hbc + (size_t)((t + 1) & 1) * 131072;
      size_t widx = (size_t)(b0 + grow) * 1024 + gcol;
      if (fast) st2_l2(wH + widx, f2bf(h));
      else      st2_mall(wH + widx, f2bf(h));
      out[(size_t)t * 131072 + widx] = h;              // after h store (program order)
      asm volatile("s_waitcnt vmcnt(1)" ::: "memory"); // h acked; out in flight
    }
    __syncthreads();                                   // B2

    if (tid == 0) {
      if (fast) add1_l2(cnt);
      else      add1_mall(cnt);
    }

    if (t < 255) {
      // ---- x[t+1] staging issue (plain cached loads); overlaps the poll ----
      size_t xb = (size_t)(t + 1) * 131072;
      s16x8 x0 = *(const s16x8*)(xbf + xb + s_goff[0]);
      s16x8 x1 = *(const s16x8*)(xbf + xb + s_goff[1]);
      s16x8 x2 = *(const s16x8*)(xbf + xb + s_goff[2]);
      s16x8 x3 = *(const s16x8*)(xbf + xb + s_goff[3]);

      // wv7/lane0 polls the single bg counter (arrive precedes poll!)
      if (wv == 7 && lane == 0) {
        unsigned tgt = 32u * (unsigned)(t + 1);
        if (fast) {
          while (poll_l2(cnt) < tgt) {}
        } else {
          while (poll_mall(cnt) < tgt) __builtin_amdgcn_s_sleep(1);
        }
      }
      *(s16x8*)(xbuf + s_loff[0]) = x0;
      *(s16x8*)(xbuf + s_loff[1]) = x1;
      *(s16x8*)(xbuf + s_loff[2]) = x2;
      *(s16x8*)(xbuf + s_loff[3]) = x3;
      __syncthreads();                                 // S2

      // ---- stage h[t+1] into hbuf (coalesced L2 loads, swizzled LDS) ----
      const unsigned short* hs = hbc + (size_t)((t + 1) & 1) * 131072;
      s16x8 v0, v1, v2, v3;
      if (fast) {
        v0 = ld16_l2(hs + s_goff[0]); v1 = ld16_l2(hs + s_goff[1]);
        v2 = ld16_l2(hs + s_goff[2]); v3 = ld16_l2(hs + s_goff[3]);
      } else {
        v0 = ld16_mall(hs + s_goff[0]); v1 = ld16_mall(hs + s_goff[1]);
        v2 = ld16_mall(hs + s_goff[2]); v3 = ld16_mall(hs + s_goff[3]);
      }
      asm volatile("s_waitcnt vmcnt(0)" ::: "memory");
      *(s16x8*)(hbuf + s_loff[0]) = v0;
      *(s16x8*)(hbuf + s_loff[1]) = v1;
      *(s16x8*)(hbuf + s_loff[2]) = v2;
      *(s16x8*)(hbuf + s_loff[3]) = v3;
      __syncthreads();                                 // S3
    }
  }
}

extern "C" void kernel_launch(void* const* d_in, const int* in_sizes, int n_in,
                              void* d_out, int out_size, void* d_ws, size_t ws_size,
                              hipStream_t stream) {
  const float* x   = (const float*)d_in[0];
  const float* wih = (const float*)d_in[1];
  const float* whh = (const float*)d_in[2];
  const float* bih = (const float*)d_in[3];
  const float* bhh = (const float*)d_in[4];
  float* out = (float*)d_out;

  char* ws = (char*)d_ws;
  unsigned short* xbf = (unsigned short*)ws;                      // 64 MiB
  unsigned short* hbc = (unsigned short*)(ws + 67108864);         // 512 KiB
  unsigned int*   bar = (unsigned int*)(ws + 67633152);           // 40 KiB

  hipMemsetAsync(bar, 0, 40960, stream);    // counters + det flags
  cvt_bf16<<<2048, 256, 0, stream>>>(x, xbf, 32768 * 1024 / 4);
  gru_scan<<<256, 512, 0, stream>>>(xbf, whh, wih, bhh, bih, out, hbc, bar);
}